// Round 4
// baseline (121.886 us; speedup 1.0000x reference)
//
#include <hip/hip_runtime.h>
#include <math.h>

#define KMAX  64
#define HSZ   256        // local (LDS) hash size
#define GHSZ  256        // global per-batch hash size
#define NBLK  256        // blocks per batch (512 total @B=2 -> 2/CU, co-resident)
#define EMPTY 0xFFFFFFFFu
#define SENT  0xFFFFFFFFu
#define LAM   300.0f

struct GTab {
    unsigned key[GHSZ];
    unsigned cnt[GHSZ];
    float s0[GHSZ], s1[GHSZ], s2[GHSZ];
};
struct Ctrl {
    unsigned arrive[8];   // per-batch phase-1 barrier
    unsigned tk[8];       // per-batch finisher tickets
    unsigned tkF;         // global finisher ticket
    unsigned pad[3];
    float batch_loss[8];
};

__device__ __forceinline__ unsigned key_of(float r, float g, float b) {
    return ((unsigned)r << 16) | ((unsigned)g << 8) | (unsigned)b;
}

__device__ __forceinline__ int hfi_lds(unsigned* hkey, unsigned key) {
    unsigned s = (key * 2654435761u) >> 24;
    while (true) {
        unsigned cur = *(volatile unsigned*)&hkey[s];
        if (cur == key) return (int)s;
        if (cur == EMPTY) {
            unsigned old = atomicCAS(&hkey[s], EMPTY, key);
            if (old == EMPTY || old == key) return (int)s;
        } else {
            s = (s + 1) & (HSZ - 1);
        }
    }
}

__device__ __forceinline__ int hfi_glb(unsigned* gkey, unsigned key) {
    unsigned s = (key * 2654435761u) >> 24;
    while (true) {
        unsigned old = atomicCAS(&gkey[s], EMPTY, key);
        if (old == EMPTY || old == key) return (int)s;
        s = (s + 1) & (GHSZ - 1);
    }
}

__device__ __forceinline__ int lower_bound64(const unsigned* su, unsigned key) {
    int lo = 0;
    if (su[lo + 31] < key) lo += 32;
    if (su[lo + 15] < key) lo += 16;
    if (su[lo + 7]  < key) lo += 8;
    if (su[lo + 3]  < key) lo += 4;
    if (su[lo + 1]  < key) lo += 2;
    if (su[lo]      < key) lo += 1;
    return lo;
}

__device__ __forceinline__ float huber1(float e) {
    float a = fabsf(e);
    return a < 1.0f ? 0.5f * e * e : a - 0.5f;
}

__global__ __launch_bounds__(256) void k_init(GTab* gt, Ctrl* ctrl, int B) {
    int tid = threadIdx.x;
    for (int b = 0; b < B; ++b) {
        GTab* g = &gt[b];
        g->key[tid] = EMPTY;
        g->cnt[tid] = 0u;
        g->s0[tid] = 0.f; g->s1[tid] = 0.f; g->s2[tid] = 0.f;
    }
    if (tid < 8) { ctrl->arrive[tid] = 0u; ctrl->tk[tid] = 0u; }
    if (tid == 0) ctrl->tkF = 0u;
}

__global__ __launch_bounds__(256) void k_fused(const float* __restrict__ pred,
        const float* __restrict__ tgt, GTab* __restrict__ gt,
        float* __restrict__ partial2, Ctrl* __restrict__ ctrl,
        const unsigned char* __restrict__ no_bg, float* __restrict__ out,
        int P, int B)
{
    int b = blockIdx.y, bx = blockIdx.x, tid = threadIdx.x;
    const float* tg = tgt + (size_t)b * 3 * P;
    const float* pr = pred + (size_t)b * 3 * P;
    GTab* g = &gt[b];

    __shared__ unsigned hkey[HSZ];          // phase1 local hash; phase2: cand keys
    __shared__ unsigned scnt[HSZ];          // phase1 counts;     phase2: cand pos
    __shared__ float ss0[HSZ], ss1[HSZ], ss2[HSZ];
    __shared__ unsigned su[KMAX];
    __shared__ int spos[KMAX];
    __shared__ float4 smv[KMAX];            // {m0,m1,m2, LAM*a_k}
    __shared__ float4 srv[KMAX];            // {bg-zeroed means, w_h}
    __shared__ int scnted[KMAX];
    __shared__ int sct, sM;
    __shared__ unsigned cc;
    __shared__ double dred[256];
    __shared__ float wred[4];
    __shared__ int amLast;

    hkey[tid] = EMPTY;
    scnt[tid] = 0u;
    ss0[tid] = 0.f; ss1[tid] = 0.f; ss2[tid] = 0.f;
    __syncthreads();

    // ---------------- phase 1: local accumulate -----------------------------
    int ngrp = P >> 2;
    int gidx = bx * 256 + tid;
    bool v0 = gidx < ngrp;
    unsigned kk[4];
    float q0[4], q1[4], q2[4];
    if (v0) {
        float4 tr = *(const float4*)(tg + 4 * (size_t)gidx);
        float4 tc = *(const float4*)(tg + P + 4 * (size_t)gidx);
        float4 tb = *(const float4*)(tg + 2 * P + 4 * (size_t)gidx);
        float4 pa = *(const float4*)(pr + 4 * (size_t)gidx);
        float4 pb = *(const float4*)(pr + P + 4 * (size_t)gidx);
        float4 pc = *(const float4*)(pr + 2 * P + 4 * (size_t)gidx);
        kk[0] = key_of(tr.x, tc.x, tb.x); kk[1] = key_of(tr.y, tc.y, tb.y);
        kk[2] = key_of(tr.z, tc.z, tb.z); kk[3] = key_of(tr.w, tc.w, tb.w);
        q0[0]=pa.x; q0[1]=pa.y; q0[2]=pa.z; q0[3]=pa.w;
        q1[0]=pb.x; q1[1]=pb.y; q1[2]=pb.z; q1[3]=pb.w;
        q2[0]=pc.x; q2[1]=pc.y; q2[2]=pc.z; q2[3]=pc.w;
        #pragma unroll
        for (int j = 0; j < 4; ++j) {
            int s = hfi_lds(hkey, kk[j]);
            atomicAdd(&scnt[s], 1u);
            atomicAdd(&ss0[s], q0[j]);
            atomicAdd(&ss1[s], q1[j]);
            atomicAdd(&ss2[s], q2[j]);
        }
    }
    // overflow groups (only if ngrp > NBLK*256): accumulate now, reload later
    for (int g2 = NBLK * 256 + bx * 256 + tid; g2 < ngrp; g2 += NBLK * 256) {
        float4 tr = *(const float4*)(tg + 4 * (size_t)g2);
        float4 tc = *(const float4*)(tg + P + 4 * (size_t)g2);
        float4 tb = *(const float4*)(tg + 2 * P + 4 * (size_t)g2);
        float4 pa = *(const float4*)(pr + 4 * (size_t)g2);
        float4 pb = *(const float4*)(pr + P + 4 * (size_t)g2);
        float4 pc = *(const float4*)(pr + 2 * P + 4 * (size_t)g2);
        float t0[4] = {tr.x,tr.y,tr.z,tr.w}, t1[4] = {tc.x,tc.y,tc.z,tc.w};
        float t2[4] = {tb.x,tb.y,tb.z,tb.w};
        float p0[4] = {pa.x,pa.y,pa.z,pa.w}, p1[4] = {pb.x,pb.y,pb.z,pb.w};
        float p2[4] = {pc.x,pc.y,pc.z,pc.w};
        #pragma unroll
        for (int j = 0; j < 4; ++j) {
            int s = hfi_lds(hkey, key_of(t0[j], t1[j], t2[j]));
            atomicAdd(&scnt[s], 1u);
            atomicAdd(&ss0[s], p0[j]);
            atomicAdd(&ss1[s], p1[j]);
            atomicAdd(&ss2[s], p2[j]);
        }
    }
    __syncthreads();

    // flush local partials into the per-batch global hash
    {
        unsigned key = hkey[tid];
        if (key != EMPTY) {
            int gp = hfi_glb(g->key, key);
            atomicAdd(&g->cnt[gp], scnt[tid]);
            atomicAdd(&g->s0[gp], ss0[tid]);
            atomicAdd(&g->s1[gp], ss1[tid]);
            atomicAdd(&g->s2[gp], ss2[tid]);
        }
    }
    __syncthreads();

    // ---------------- per-batch barrier (all blocks co-resident) ------------
    if (tid == 0) {
        __hip_atomic_fetch_add(&ctrl->arrive[b], 1u,
                               __ATOMIC_ACQ_REL, __HIP_MEMORY_SCOPE_AGENT);
        while (__hip_atomic_load(&ctrl->arrive[b],
                                 __ATOMIC_ACQUIRE, __HIP_MEMORY_SCOPE_AGENT)
               < (unsigned)NBLK)
            __builtin_amdgcn_s_sleep(2);
    }
    __syncthreads();

    // ---------------- phase 2: every block derives segment constants --------
    if (tid == 0) cc = 0u;
    if (tid < KMAX) su[tid] = SENT;
    __syncthreads();
    {   // compact global table (reuse hkey/scnt as candidate arrays)
        unsigned key = __hip_atomic_load(&g->key[tid],
                                         __ATOMIC_RELAXED, __HIP_MEMORY_SCOPE_AGENT);
        if (key != EMPTY) {
            unsigned pos = atomicAdd(&cc, 1u);
            hkey[pos] = key;
            scnt[pos] = (unsigned)tid;
        }
    }
    __syncthreads();
    int C = (int)cc;
    if (tid < C) {
        unsigned key = hkey[tid];
        int rank = 0;
        for (int j = 0; j < C; ++j) rank += (hkey[j] < key) ? 1 : 0;
        if (rank < KMAX) { su[rank] = key; spos[rank] = (int)scnt[tid]; }
    }
    __syncthreads();
    if (tid < KMAX) {
        unsigned key = su[tid];
        bool valid = key != SENT;
        unsigned c = 0u;
        float f0 = 0.f, f1 = 0.f, f2 = 0.f;
        if (valid) {
            int i = spos[tid];
            c  = __hip_atomic_load(&g->cnt[i], __ATOMIC_RELAXED, __HIP_MEMORY_SCOPE_AGENT);
            f0 = __hip_atomic_load(&g->s0[i], __ATOMIC_RELAXED, __HIP_MEMORY_SCOPE_AGENT);
            f1 = __hip_atomic_load(&g->s1[i], __ATOMIC_RELAXED, __HIP_MEMORY_SCOPE_AGENT);
            f2 = __hip_atomic_load(&g->s2[i], __ATOMIC_RELAXED, __HIP_MEMORY_SCOPE_AGENT);
        }
        float n = (c > 0u) ? (float)c : 1.0f;
        float inv_n = 1.0f / n;
        float m0 = f0 * inv_n, m1 = f1 * inv_n, m2 = f2 * inv_n;
        bool isbg = valid && (key == 0u);
        bool nb = no_bg[b] != 0;
        bool counted = valid && (c > 0u) && (!isbg || !nb);
        long n_out = (long)P - (long)c;
        bool active = valid && (c > 0u) && !isbg && (n_out > 0);
        float noutf = (n_out > 0) ? (float)n_out : 1.0f;
        float saw = active ? (LAM * 10.0f / (sqrtf(n) * noutf)) : 0.0f;
        float whw = counted ? (1.0f / (3.0f * n)) : 0.0f;
        smv[tid] = make_float4(m0, m1, m2, saw);
        srv[tid] = make_float4(isbg ? 0.f : m0, isbg ? 0.f : m1, isbg ? 0.f : m2, whw);
        scnted[tid] = counted ? 1 : 0;
        unsigned long long mc = __ballot(counted);
        unsigned long long mv = __ballot(valid);
        if (tid == 0) { sct = (int)__popcll(mc); sM = (int)__popcll(mv); }
    }
    __syncthreads();

    // ---------------- phase 3: P x K main loop (pixels still in regs) -------
    float accs = 0.f;
    const int M2 = sM;
    if (v0) {
        int sid[4]; float fa[4];
        #pragma unroll
        for (int j = 0; j < 4; ++j) {
            int lo = lower_bound64(su, kk[j]);
            sid[j] = lo;
            float4 rv = srv[lo];
            accs += rv.w * (huber1(q0[j] - rv.x) + huber1(q1[j] - rv.y)
                            + huber1(q2[j] - rv.z));
            fa[j] = 0.f;
        }
        for (int k = 0; k < M2; ++k) {
            float4 vv = smv[k];
            #pragma unroll
            for (int j = 0; j < 4; ++j) {
                float e0 = q0[j] - vv.x, e1 = q1[j] - vv.y, e2 = q2[j] - vv.z;
                float d = fmaf(e0, e0, fmaf(e1, e1, e2 * e2));
                fa[j] = fmaf(vv.w, __builtin_amdgcn_rcpf(1.0f + d), fa[j]);
            }
        }
        #pragma unroll
        for (int j = 0; j < 4; ++j) {
            float4 vv = smv[sid[j]];
            float e0 = q0[j] - vv.x, e1 = q1[j] - vv.y, e2 = q2[j] - vv.z;
            float d = fmaf(e0, e0, fmaf(e1, e1, e2 * e2));
            accs += fa[j] - vv.w * __builtin_amdgcn_rcpf(1.0f + d);
        }
    }
    // overflow groups: reload and process
    for (int g2 = NBLK * 256 + bx * 256 + tid; g2 < ngrp; g2 += NBLK * 256) {
        float4 tr = *(const float4*)(tg + 4 * (size_t)g2);
        float4 tc = *(const float4*)(tg + P + 4 * (size_t)g2);
        float4 tb = *(const float4*)(tg + 2 * P + 4 * (size_t)g2);
        float4 pa = *(const float4*)(pr + 4 * (size_t)g2);
        float4 pb = *(const float4*)(pr + P + 4 * (size_t)g2);
        float4 pc = *(const float4*)(pr + 2 * P + 4 * (size_t)g2);
        float t0[4] = {tr.x,tr.y,tr.z,tr.w}, t1[4] = {tc.x,tc.y,tc.z,tc.w};
        float t2[4] = {tb.x,tb.y,tb.z,tb.w};
        float p0[4] = {pa.x,pa.y,pa.z,pa.w}, p1[4] = {pb.x,pb.y,pb.z,pb.w};
        float p2[4] = {pc.x,pc.y,pc.z,pc.w};
        int sid[4]; float fa[4];
        #pragma unroll
        for (int j = 0; j < 4; ++j) {
            int lo = lower_bound64(su, key_of(t0[j], t1[j], t2[j]));
            sid[j] = lo;
            float4 rv = srv[lo];
            accs += rv.w * (huber1(p0[j] - rv.x) + huber1(p1[j] - rv.y)
                            + huber1(p2[j] - rv.z));
            fa[j] = 0.f;
        }
        for (int k = 0; k < M2; ++k) {
            float4 vv = smv[k];
            #pragma unroll
            for (int j = 0; j < 4; ++j) {
                float e0 = p0[j] - vv.x, e1 = p1[j] - vv.y, e2 = p2[j] - vv.z;
                float d = fmaf(e0, e0, fmaf(e1, e1, e2 * e2));
                fa[j] = fmaf(vv.w, __builtin_amdgcn_rcpf(1.0f + d), fa[j]);
            }
        }
        #pragma unroll
        for (int j = 0; j < 4; ++j) {
            float4 vv = smv[sid[j]];
            float e0 = p0[j] - vv.x, e1 = p1[j] - vv.y, e2 = p2[j] - vv.z;
            float d = fmaf(e0, e0, fmaf(e1, e1, e2 * e2));
            accs += fa[j] - vv.w * __builtin_amdgcn_rcpf(1.0f + d);
        }
    }

    // ---------------- phase 4: reduce + finishers ---------------------------
    #pragma unroll
    for (int o = 32; o > 0; o >>= 1) accs += __shfl_xor(accs, o);
    int lane = tid & 63, wid = tid >> 6;
    if (lane == 0) wred[wid] = accs;
    __syncthreads();
    if (tid == 0) {
        float tot = wred[0] + wred[1] + wred[2] + wred[3];
        __hip_atomic_store(&partial2[(size_t)b * NBLK + bx], tot,
                           __ATOMIC_RELEASE, __HIP_MEMORY_SCOPE_AGENT);
        unsigned old = __hip_atomic_fetch_add(&ctrl->tk[b], 1u,
                           __ATOMIC_ACQ_REL, __HIP_MEMORY_SCOPE_AGENT);
        amLast = (old == (unsigned)(NBLK - 1)) ? 1 : 0;
    }
    __syncthreads();
    if (!amLast) return;

    // last block of this batch: deterministic reduce + pairwise + combine
    {
        double dv = 0.0;
        if (tid < NBLK)
            dv = (double)__hip_atomic_load(&partial2[(size_t)b * NBLK + tid],
                                           __ATOMIC_ACQUIRE, __HIP_MEMORY_SCOPE_AGENT);
        dred[tid] = dv;
        __syncthreads();
        for (int s = 128; s > 0; s >>= 1) {
            if (tid < s) dred[tid] += dred[tid + s];
            __syncthreads();
        }
    }

    float rs = 0.f;
    if (tid < KMAX && scnted[tid]) {
        float4 a = srv[tid];
        for (int j = 0; j < KMAX; ++j) {
            if (j == tid || !scnted[j]) continue;
            float4 c2 = srv[j];
            float d0 = a.x - c2.x, d1 = a.y - c2.y, d2 = a.z - c2.z;
            rs += LAM / (d0 * d0 + d1 * d1 + d2 * d2 + 1.0f);
        }
    }
    #pragma unroll
    for (int o = 32; o > 0; o >>= 1) rs += __shfl_xor(rs, o);

    if (tid == 0) {
        int ct = sct;
        float ctf = (float)ct;
        float npairs = ctf * (ctf - 1.0f) * 0.5f;
        float mean_sep = (ct > 1) ? (rs * 0.5f / fmaxf(npairs, 1.0f)) : 0.0f;
        float loss = ((float)dred[0] + mean_sep) / fmaxf(ctf, 1.0f);
        __hip_atomic_store(&ctrl->batch_loss[b], loss,
                           __ATOMIC_RELEASE, __HIP_MEMORY_SCOPE_AGENT);
        unsigned old2 = __hip_atomic_fetch_add(&ctrl->tkF, 1u,
                            __ATOMIC_ACQ_REL, __HIP_MEMORY_SCOPE_AGENT);
        if (old2 == (unsigned)(B - 1)) {
            float s = 0.f;
            for (int i = 0; i < B; ++i)
                s += __hip_atomic_load(&ctrl->batch_loss[i],
                                       __ATOMIC_ACQUIRE, __HIP_MEMORY_SCOPE_AGENT);
            out[0] = s / (float)B;
        }
    }
}

extern "C" void kernel_launch(void* const* d_in, const int* in_sizes, int n_in,
                              void* d_out, int out_size, void* d_ws, size_t ws_size,
                              hipStream_t stream) {
    const float* pred = (const float*)d_in[0];
    const float* tgt  = (const float*)d_in[1];
    const unsigned char* nb = (const unsigned char*)d_in[2];
    float* out = (float*)d_out;

    int B = in_sizes[2];
    int P = in_sizes[0] / (3 * B);

    char* wsb = (char*)d_ws;
    GTab* gt = (GTab*)wsb;
    size_t gtBytes = (size_t)B * sizeof(GTab);
    Ctrl* ctrl = (Ctrl*)(wsb + ((gtBytes + 255) & ~(size_t)255));
    float* partial2 = (float*)((char*)ctrl + ((sizeof(Ctrl) + 255) & ~(size_t)255));

    k_init <<<1, 256, 0, stream>>>(gt, ctrl, B);
    k_fused<<<dim3(NBLK, B), 256, 0, stream>>>(pred, tgt, gt, partial2, ctrl,
                                               nb, out, P, B);
}